// Round 4
// baseline (303.832 us; speedup 1.0000x reference)
//
#include <hip/hip_runtime.h>
#include <math.h>

#define N_NODES 100000

typedef unsigned short bfu;
typedef unsigned int uint;

__device__ __forceinline__ float bf2f(bfu u) {
    union { uint i; float f; } v; v.i = (uint)u << 16; return v.f;
}
__device__ __forceinline__ bfu f2bf(float f) {   // round-to-nearest-even
    union { float f_; uint i; } v; v.f_ = f;
    uint r = (v.i + 0x7FFFu + ((v.i >> 16) & 1u)) >> 16;
    return (bfu)r;
}

// ---------------------------------------------------------------- degree histogram (int)
__global__ void count_deg(const int* __restrict__ dst, int* __restrict__ deg, int nE) {
    int e = blockIdx.x * blockDim.x + threadIdx.x;
    if (e < nE) atomicAdd(&deg[dst[e]], 1);
}

__global__ void finish_dinv(const int* __restrict__ deg, float* __restrict__ dinv, int n) {
    int i = blockIdx.x * blockDim.x + threadIdx.x;
    if (i < n) dinv[i] = rsqrtf((float)deg[i] + 1.0f);  // +1 = self loop
}

// ---------------------------------------------------------------- exclusive scan (3 kernels)
__global__ void scan_local(const int* __restrict__ deg, int* __restrict__ rowptr,
                           int* __restrict__ partials, int n) {
    __shared__ int s[256];
    int i = blockIdx.x * 256 + threadIdx.x;
    int v = (i < n) ? deg[i] : 0;
    s[threadIdx.x] = v;
    __syncthreads();
    #pragma unroll
    for (int off = 1; off < 256; off <<= 1) {
        int t = (threadIdx.x >= off) ? s[threadIdx.x - off] : 0;
        __syncthreads();
        s[threadIdx.x] += t;
        __syncthreads();
    }
    if (i <= n) rowptr[i] = s[threadIdx.x] - v;   // exclusive
    if (threadIdx.x == 255) partials[blockIdx.x] = s[255];
}

__global__ void scan_partials(int* __restrict__ partials, int nB) {
    __shared__ int s[512];
    int v = (threadIdx.x < nB) ? partials[threadIdx.x] : 0;
    s[threadIdx.x] = v;
    __syncthreads();
    #pragma unroll
    for (int off = 1; off < 512; off <<= 1) {
        int t = (threadIdx.x >= off) ? s[threadIdx.x - off] : 0;
        __syncthreads();
        s[threadIdx.x] += t;
        __syncthreads();
    }
    if (threadIdx.x < nB) partials[threadIdx.x] = s[threadIdx.x] - v;
}

__global__ void add_offsets(int* __restrict__ rowptr, const int* __restrict__ partials, int m) {
    int i = blockIdx.x * 256 + threadIdx.x;
    if (i < m) rowptr[i] += partials[blockIdx.x];
}

// ---------------------------------------------------------------- scatter edges into CSR
__global__ void scatter_edges(const int* __restrict__ src, const int* __restrict__ dst,
                              const int* __restrict__ rowptr, int* __restrict__ cursor,
                              int* __restrict__ nbr, int nE) {
    int e = blockIdx.x * blockDim.x + threadIdx.x;
    if (e >= nE) return;
    int d = dst[e];
    int pos = rowptr[d] + atomicAdd(&cursor[d], 1);
    nbr[pos] = src[e];
}

// ---------------------------------------------------------------- z0 = bf16(dinv * x)
__global__ void scale_to_bf16(ushort4* __restrict__ z0, const float4* __restrict__ x,
                              const float* __restrict__ dinv, int n4) {
    int t = blockIdx.x * blockDim.x + threadIdx.x;
    if (t >= n4) return;
    float w = dinv[t >> 4];
    float4 v = x[t];
    ushort4 o;
    o.x = f2bf(w * v.x); o.y = f2bf(w * v.y);
    o.z = f2bf(w * v.z); o.w = f2bf(w * v.w);
    z0[t] = o;
}

// ---------------------------------------------------------------- gather hop (bf16 in/out)
// out = bf16( dinv^PW * (z[self] + sum_nbr z[s]) )
template<int PW>
__global__ __launch_bounds__(256) void gather_hop_bf16(
    bfu* __restrict__ out, const bfu* __restrict__ z,
    const int* __restrict__ nbr, const int* __restrict__ rowptr,
    const float* __restrict__ dinv, int nN) {
    int node = blockIdx.x * 4 + (threadIdx.x >> 6);
    if (node >= nN) return;
    int lane = threadIdx.x & 63;
    int beg = rowptr[node], end = rowptr[node + 1];
    float di = dinv[node];
    float a0 = bf2f(z[(size_t)node * 64 + lane]);   // self loop
    float a1 = 0.f, a2 = 0.f, a3 = 0.f;
    int j = beg;
    for (; j + 4 <= end; j += 4) {                  // 4 outstanding row loads
        int s0 = nbr[j], s1 = nbr[j + 1], s2 = nbr[j + 2], s3 = nbr[j + 3];
        a0 += bf2f(z[(size_t)s0 * 64 + lane]);
        a1 += bf2f(z[(size_t)s1 * 64 + lane]);
        a2 += bf2f(z[(size_t)s2 * 64 + lane]);
        a3 += bf2f(z[(size_t)s3 * 64 + lane]);
    }
    for (; j < end; ++j)
        a0 += bf2f(z[(size_t)nbr[j] * 64 + lane]);
    float w = (PW == 2) ? di * di : di;
    out[(size_t)node * 64 + lane] = f2bf((a0 + a1 + a2 + a3) * w);
}

// ---------------------------------------------------------------- fused MLP + log_softmax
// block = 256 threads = 64 nodes; register-tiled 4x4 GEMM, h round-trips via LDS
__global__ __launch_bounds__(256) void mlp_fused(
    float* __restrict__ out, const bfu* __restrict__ xin,
    const float* __restrict__ W1, const float* __restrict__ b1,
    const float* __restrict__ W2, const float* __restrict__ b2, int nN) {
    __shared__ float xT[64][68];    // xT[k][n]
    __shared__ float W1s[64][64];
    __shared__ float W2s[64][40];
    __shared__ float b1s[64];
    __shared__ float b2s[40];
    int tid = threadIdx.x;
    int base = blockIdx.x * 64;

    for (int i = tid; i < 64 * 64; i += 256) W1s[i >> 6][i & 63] = W1[i];
    for (int i = tid; i < 64 * 40; i += 256) W2s[i / 40][i % 40] = W2[i];
    if (tid < 64) b1s[tid] = b1[tid];
    if (tid >= 64 && tid < 104) b2s[tid - 64] = b2[tid - 64];

    {   // load 64-node bf16 tile transposed; dword = 2 features, coalesced
        const uint* xr = (const uint*)(xin + (size_t)base * 64);
        int limit = (nN - base >= 64) ? 64 * 32 : (nN - base) * 32;
        for (int i = tid; i < 64 * 32; i += 256) {
            uint v = (i < limit) ? xr[i] : 0u;
            int n = i >> 5, kk = (i & 31) * 2;
            union { uint u; float f; } lo, hi;
            lo.u = v << 16; hi.u = v & 0xFFFF0000u;
            xT[kk + 0][n] = lo.f;
            xT[kk + 1][n] = hi.f;
        }
    }
    __syncthreads();

    // stage 1: h = relu(x @ W1 + b1); thread owns 4 nodes x 4 hids
    int h0 = (tid & 15) * 4, n0 = (tid >> 4) * 4;
    float acc[4][4];
    #pragma unroll
    for (int i = 0; i < 4; ++i)
        #pragma unroll
        for (int j = 0; j < 4; ++j) acc[i][j] = b1s[h0 + j];
    #pragma unroll 8
    for (int k = 0; k < 64; ++k) {
        float4 xv = *reinterpret_cast<const float4*>(&xT[k][n0]);
        float4 wv = *reinterpret_cast<const float4*>(&W1s[k][h0]);
        acc[0][0] = fmaf(xv.x, wv.x, acc[0][0]);
        acc[0][1] = fmaf(xv.x, wv.y, acc[0][1]);
        acc[0][2] = fmaf(xv.x, wv.z, acc[0][2]);
        acc[0][3] = fmaf(xv.x, wv.w, acc[0][3]);
        acc[1][0] = fmaf(xv.y, wv.x, acc[1][0]);
        acc[1][1] = fmaf(xv.y, wv.y, acc[1][1]);
        acc[1][2] = fmaf(xv.y, wv.z, acc[1][2]);
        acc[1][3] = fmaf(xv.y, wv.w, acc[1][3]);
        acc[2][0] = fmaf(xv.z, wv.x, acc[2][0]);
        acc[2][1] = fmaf(xv.z, wv.y, acc[2][1]);
        acc[2][2] = fmaf(xv.z, wv.z, acc[2][2]);
        acc[2][3] = fmaf(xv.z, wv.w, acc[2][3]);
        acc[3][0] = fmaf(xv.w, wv.x, acc[3][0]);
        acc[3][1] = fmaf(xv.w, wv.y, acc[3][1]);
        acc[3][2] = fmaf(xv.w, wv.z, acc[3][2]);
        acc[3][3] = fmaf(xv.w, wv.w, acc[3][3]);
    }
    __syncthreads();
    #pragma unroll
    for (int i = 0; i < 4; ++i)
        #pragma unroll
        for (int j = 0; j < 4; ++j)
            xT[h0 + j][n0 + i] = fmaxf(acc[i][j], 0.f);   // hT[hid][node]
    __syncthreads();

    // stage 2: logits + log_softmax; 4 threads per node, 10 classes each
    int n2 = tid >> 2, q = tid & 3;
    float lg[10];
    #pragma unroll
    for (int c = 0; c < 10; ++c) lg[c] = b2s[q * 10 + c];
    #pragma unroll 4
    for (int k = 0; k < 64; ++k) {
        float hv = xT[k][n2];
        #pragma unroll
        for (int c = 0; c < 10; ++c)
            lg[c] = fmaf(hv, W2s[k][q * 10 + c], lg[c]);
    }
    float m = lg[0];
    #pragma unroll
    for (int c = 1; c < 10; ++c) m = fmaxf(m, lg[c]);
    m = fmaxf(m, __shfl_xor(m, 1));
    m = fmaxf(m, __shfl_xor(m, 2));
    float s = 0.f;
    #pragma unroll
    for (int c = 0; c < 10; ++c) s += expf(lg[c] - m);
    s += __shfl_xor(s, 1);
    s += __shfl_xor(s, 2);
    float lse = m + logf(s);
    int gn = base + n2;
    if (gn < nN) {
        #pragma unroll
        for (int c = 0; c < 10; ++c)
            out[(size_t)gn * 40 + q * 10 + c] = lg[c] - lse;
    }
}

extern "C" void kernel_launch(void* const* d_in, const int* in_sizes, int n_in,
                              void* d_out, int out_size, void* d_ws, size_t ws_size,
                              hipStream_t stream) {
    const float* x   = (const float*)d_in[0];
    const int* eidx  = (const int*)d_in[1];
    const float* W1  = (const float*)d_in[2];
    const float* b1  = (const float*)d_in[3];
    const float* W2  = (const float*)d_in[4];
    const float* b2  = (const float*)d_in[5];
    float* out = (float*)d_out;

    const int nN = N_NODES;
    const int nE = in_sizes[1] / 2;  // edge_index is [2, E]
    const int* src = eidx;
    const int* dst = eidx + nE;

    // ---- workspace layout (256B aligned)
    char* ws = (char*)d_ws;
    size_t off = 0;
    auto alloc = [&](size_t bytes) {
        char* p = ws + off;
        off += (bytes + 255) & ~(size_t)255;
        return p;
    };
    float* dinv    = (float*)alloc((size_t)nN * 4);
    int*   deg     = (int*)  alloc((size_t)nN * 4);      // reused as scatter cursor
    int*   rowptr  = (int*)  alloc((size_t)(nN + 1) * 4);
    int*   partials= (int*)  alloc(512 * 4);
    int*   nbr     = (int*)  alloc((size_t)nE * 4);
    bfu*   z0      = (bfu*)  alloc((size_t)nN * 64 * 2);
    bfu*   zB      = (bfu*)  alloc((size_t)nN * 64 * 2);
    bfu*   zC      = (bfu*)  alloc((size_t)nN * 64 * 2);

    const int nB = (nN + 1 + 255) / 256;

    // 1. degree histogram + dinv
    hipMemsetAsync(deg, 0, (size_t)nN * 4, stream);
    count_deg<<<(nE + 255) / 256, 256, 0, stream>>>(dst, deg, nE);
    finish_dinv<<<(nN + 255) / 256, 256, 0, stream>>>(deg, dinv, nN);

    // 2. rowptr = exclusive scan(deg)
    scan_local<<<nB, 256, 0, stream>>>(deg, rowptr, partials, nN);
    scan_partials<<<1, 512, 0, stream>>>(partials, nB);
    add_offsets<<<nB, 256, 0, stream>>>(rowptr, partials, nN + 1);

    // 3. scatter edges into CSR (deg reused as cursor)
    hipMemsetAsync(deg, 0, (size_t)nN * 4, stream);
    scatter_edges<<<(nE + 255) / 256, 256, 0, stream>>>(src, dst, rowptr, deg, nbr, nE);

    // 4. z0 = bf16(D^-1/2 x); two unweighted gather hops with diagonal scales:
    //    zB = bf16(D^-1 (A+I) z0); zC = bf16(D^-1/2 (A+I) zB)
    const int n4 = nN * 16;
    scale_to_bf16<<<(n4 + 255) / 256, 256, 0, stream>>>((ushort4*)z0, (const float4*)x, dinv, n4);
    const int gBlocks = (nN + 3) / 4;
    gather_hop_bf16<2><<<gBlocks, 256, 0, stream>>>(zB, z0, nbr, rowptr, dinv, nN);
    gather_hop_bf16<1><<<gBlocks, 256, 0, stream>>>(zC, zB, nbr, rowptr, dinv, nN);

    // 5. fused MLP + log_softmax
    mlp_fused<<<(nN + 63) / 64, 256, 0, stream>>>(out, zC, W1, b1, W2, b2, nN);
}

// Round 5
// 213.822 us; speedup vs baseline: 1.4210x; 1.4210x over previous
//
#include <hip/hip_runtime.h>
#include <math.h>

#define N_NODES 100000
#define BSHIFT 9                 // 512-node buckets
#define NBUCK 256                // >= ceil(N/512)=196, pow2 for arrays

typedef unsigned short bfu;
typedef unsigned int uint;

__device__ __forceinline__ float bf2f(bfu u) {
    union { uint i; float f; } v; v.i = (uint)u << 16; return v.f;
}
__device__ __forceinline__ bfu f2bf(float f) {   // round-to-nearest-even
    union { float f_; uint i; } v; v.f_ = f;
    uint r = (v.i + 0x7FFFu + ((v.i >> 16) & 1u)) >> 16;
    return (bfu)r;
}

// ---------------------------------------------------------------- P0: bucket histogram
__global__ __launch_bounds__(256) void bucket_hist(const int* __restrict__ dst,
                                                   int* __restrict__ gcount, int nE) {
    __shared__ int h[NBUCK];
    int tid = threadIdx.x;
    h[tid] = 0;
    __syncthreads();
    for (int e = blockIdx.x * 256 + tid; e < nE; e += gridDim.x * 256)
        atomicAdd(&h[dst[e] >> BSHIFT], 1);
    __syncthreads();
    if (h[tid]) atomicAdd(&gcount[tid], h[tid]);
}

// ---------------------------------------------------------------- P0b: scan bucket counts
__global__ __launch_bounds__(NBUCK) void scan_buckets(const int* __restrict__ gcount,
                                                      int* __restrict__ gbase,
                                                      int* __restrict__ gcursor) {
    __shared__ int s[NBUCK];
    int t = threadIdx.x;
    int v = gcount[t];
    s[t] = v;
    __syncthreads();
    #pragma unroll
    for (int off = 1; off < NBUCK; off <<= 1) {
        int tv = (t >= off) ? s[t - off] : 0;
        __syncthreads();
        s[t] += tv;
        __syncthreads();
    }
    gbase[t] = s[t] - v;     // exclusive
    gcursor[t] = s[t] - v;
}

// ---------------------------------------------------------------- P1: bin edges by bucket
__global__ __launch_bounds__(256) void bin_edges(const int* __restrict__ src,
                                                 const int* __restrict__ dst,
                                                 int* __restrict__ gcursor,
                                                 uint* __restrict__ binned, int nE) {
    __shared__ int h[NBUCK];
    __shared__ int base[NBUCK];
    int tid = threadIdx.x;
    int start = blockIdx.x * 4096;
    h[tid] = 0;
    __syncthreads();
    int bkt[16], rnk[16];
    #pragma unroll
    for (int u = 0; u < 16; ++u) {
        int e = start + u * 256 + tid;
        bkt[u] = -1;
        if (e < nE) {
            int b = dst[e] >> BSHIFT;
            bkt[u] = b;
            rnk[u] = atomicAdd(&h[b], 1);
        }
    }
    __syncthreads();
    base[tid] = h[tid] ? atomicAdd(&gcursor[tid], h[tid]) : 0;
    __syncthreads();
    #pragma unroll
    for (int u = 0; u < 16; ++u) {
        int e = start + u * 256 + tid;
        if (e < nE) {
            uint pk = ((uint)(dst[e] & 511) << 17) | (uint)src[e];  // src < 2^17
            binned[base[bkt[u]] + rnk[u]] = pk;
        }
    }
}

// ---------------------------------------------------------------- P2: per-bucket CSR build
// One block per 512-node bucket: local hist -> rowptr+dinv, cursor-scatter nbr
// (all nbr writes land in one ~24KB single-XCD region).
__global__ __launch_bounds__(512) void build_csr(
    const uint* __restrict__ binned, const int* __restrict__ gbase,
    const int* __restrict__ gcount, int* __restrict__ rowptr,
    float* __restrict__ dinv, int* __restrict__ nbr, int nN, int nE) {
    __shared__ int hist[512];
    __shared__ int cursor[512];
    int b = blockIdx.x, t = threadIdx.x;
    int n0 = b << BSHIFT;
    int nNodes = min(512, nN - n0);
    int base = gbase[b], cnt = gcount[b];
    hist[t] = 0;
    __syncthreads();
    for (int i = t; i < cnt; i += 512)
        atomicAdd(&hist[binned[base + i] >> 17], 1);
    __syncthreads();
    int v = hist[t];
    #pragma unroll
    for (int off = 1; off < 512; off <<= 1) {
        int tv = (t >= off) ? hist[t - off] : 0;
        __syncthreads();
        hist[t] += tv;
        __syncthreads();
    }
    int excl = hist[t] - v;
    if (t < nNodes) {
        rowptr[n0 + t] = base + excl;
        dinv[n0 + t] = rsqrtf((float)v + 1.0f);   // +1 self loop
    }
    cursor[t] = excl;
    __syncthreads();
    for (int i = t; i < cnt; i += 512) {
        uint pk = binned[base + i];
        int ld = pk >> 17;
        int pos = atomicAdd(&cursor[ld], 1);
        nbr[base + pos] = (int)(pk & 0x1FFFFu);
    }
    if (b == 0 && t == 0) rowptr[nN] = nE;
}

// ---------------------------------------------------------------- z0 = bf16(dinv * x)
__global__ void scale_to_bf16(ushort4* __restrict__ z0, const float4* __restrict__ x,
                              const float* __restrict__ dinv, int n4) {
    int t = blockIdx.x * blockDim.x + threadIdx.x;
    if (t >= n4) return;
    float w = dinv[t >> 4];
    float4 v = x[t];
    ushort4 o;
    o.x = f2bf(w * v.x); o.y = f2bf(w * v.y);
    o.z = f2bf(w * v.z); o.w = f2bf(w * v.w);
    z0[t] = o;
}

// ---------------------------------------------------------------- gather hop (bf16 in/out)
template<int PW>
__global__ __launch_bounds__(256) void gather_hop_bf16(
    bfu* __restrict__ out, const bfu* __restrict__ z,
    const int* __restrict__ nbr, const int* __restrict__ rowptr,
    const float* __restrict__ dinv, int nN) {
    int node = blockIdx.x * 4 + (threadIdx.x >> 6);
    if (node >= nN) return;
    int lane = threadIdx.x & 63;
    int beg = rowptr[node], end = rowptr[node + 1];
    float di = dinv[node];
    float a0 = bf2f(z[(size_t)node * 64 + lane]);   // self loop
    float a1 = 0.f, a2 = 0.f, a3 = 0.f;
    int j = beg;
    for (; j + 4 <= end; j += 4) {
        int s0 = nbr[j], s1 = nbr[j + 1], s2 = nbr[j + 2], s3 = nbr[j + 3];
        a0 += bf2f(z[(size_t)s0 * 64 + lane]);
        a1 += bf2f(z[(size_t)s1 * 64 + lane]);
        a2 += bf2f(z[(size_t)s2 * 64 + lane]);
        a3 += bf2f(z[(size_t)s3 * 64 + lane]);
    }
    for (; j < end; ++j)
        a0 += bf2f(z[(size_t)nbr[j] * 64 + lane]);
    float w = (PW == 2) ? di * di : di;
    out[(size_t)node * 64 + lane] = f2bf((a0 + a1 + a2 + a3) * w);
}

// ---------------------------------------------------------------- fused MLP + log_softmax
__global__ __launch_bounds__(256) void mlp_fused(
    float* __restrict__ out, const bfu* __restrict__ xin,
    const float* __restrict__ W1, const float* __restrict__ b1,
    const float* __restrict__ W2, const float* __restrict__ b2, int nN) {
    __shared__ float xT[64][68];    // xT[k][n]
    __shared__ float W1s[64][64];
    __shared__ float W2s[64][40];
    __shared__ float b1s[64];
    __shared__ float b2s[40];
    int tid = threadIdx.x;
    int base = blockIdx.x * 64;

    for (int i = tid; i < 64 * 64; i += 256) W1s[i >> 6][i & 63] = W1[i];
    for (int i = tid; i < 64 * 40; i += 256) W2s[i / 40][i % 40] = W2[i];
    if (tid < 64) b1s[tid] = b1[tid];
    if (tid >= 64 && tid < 104) b2s[tid - 64] = b2[tid - 64];

    {   // load 64-node bf16 tile transposed; dword = 2 features, coalesced
        const uint* xr = (const uint*)(xin + (size_t)base * 64);
        int limit = (nN - base >= 64) ? 64 * 32 : (nN - base) * 32;
        for (int i = tid; i < 64 * 32; i += 256) {
            uint v = (i < limit) ? xr[i] : 0u;
            int n = i >> 5, kk = (i & 31) * 2;
            union { uint u; float f; } lo, hi;
            lo.u = v << 16; hi.u = v & 0xFFFF0000u;
            xT[kk + 0][n] = lo.f;
            xT[kk + 1][n] = hi.f;
        }
    }
    __syncthreads();

    int h0 = (tid & 15) * 4, n0 = (tid >> 4) * 4;
    float acc[4][4];
    #pragma unroll
    for (int i = 0; i < 4; ++i)
        #pragma unroll
        for (int j = 0; j < 4; ++j) acc[i][j] = b1s[h0 + j];
    #pragma unroll 8
    for (int k = 0; k < 64; ++k) {
        float4 xv = *reinterpret_cast<const float4*>(&xT[k][n0]);
        float4 wv = *reinterpret_cast<const float4*>(&W1s[k][h0]);
        acc[0][0] = fmaf(xv.x, wv.x, acc[0][0]);
        acc[0][1] = fmaf(xv.x, wv.y, acc[0][1]);
        acc[0][2] = fmaf(xv.x, wv.z, acc[0][2]);
        acc[0][3] = fmaf(xv.x, wv.w, acc[0][3]);
        acc[1][0] = fmaf(xv.y, wv.x, acc[1][0]);
        acc[1][1] = fmaf(xv.y, wv.y, acc[1][1]);
        acc[1][2] = fmaf(xv.y, wv.z, acc[1][2]);
        acc[1][3] = fmaf(xv.y, wv.w, acc[1][3]);
        acc[2][0] = fmaf(xv.z, wv.x, acc[2][0]);
        acc[2][1] = fmaf(xv.z, wv.y, acc[2][1]);
        acc[2][2] = fmaf(xv.z, wv.z, acc[2][2]);
        acc[2][3] = fmaf(xv.z, wv.w, acc[2][3]);
        acc[3][0] = fmaf(xv.w, wv.x, acc[3][0]);
        acc[3][1] = fmaf(xv.w, wv.y, acc[3][1]);
        acc[3][2] = fmaf(xv.w, wv.z, acc[3][2]);
        acc[3][3] = fmaf(xv.w, wv.w, acc[3][3]);
    }
    __syncthreads();
    #pragma unroll
    for (int i = 0; i < 4; ++i)
        #pragma unroll
        for (int j = 0; j < 4; ++j)
            xT[h0 + j][n0 + i] = fmaxf(acc[i][j], 0.f);   // hT[hid][node]
    __syncthreads();

    int n2 = tid >> 2, q = tid & 3;
    float lg[10];
    #pragma unroll
    for (int c = 0; c < 10; ++c) lg[c] = b2s[q * 10 + c];
    #pragma unroll 4
    for (int k = 0; k < 64; ++k) {
        float hv = xT[k][n2];
        #pragma unroll
        for (int c = 0; c < 10; ++c)
            lg[c] = fmaf(hv, W2s[k][q * 10 + c], lg[c]);
    }
    float m = lg[0];
    #pragma unroll
    for (int c = 1; c < 10; ++c) m = fmaxf(m, lg[c]);
    m = fmaxf(m, __shfl_xor(m, 1));
    m = fmaxf(m, __shfl_xor(m, 2));
    float s = 0.f;
    #pragma unroll
    for (int c = 0; c < 10; ++c) s += expf(lg[c] - m);
    s += __shfl_xor(s, 1);
    s += __shfl_xor(s, 2);
    float lse = m + logf(s);
    int gn = base + n2;
    if (gn < nN) {
        #pragma unroll
        for (int c = 0; c < 10; ++c)
            out[(size_t)gn * 40 + q * 10 + c] = lg[c] - lse;
    }
}

extern "C" void kernel_launch(void* const* d_in, const int* in_sizes, int n_in,
                              void* d_out, int out_size, void* d_ws, size_t ws_size,
                              hipStream_t stream) {
    const float* x   = (const float*)d_in[0];
    const int* eidx  = (const int*)d_in[1];
    const float* W1  = (const float*)d_in[2];
    const float* b1  = (const float*)d_in[3];
    const float* W2  = (const float*)d_in[4];
    const float* b2  = (const float*)d_in[5];
    float* out = (float*)d_out;

    const int nN = N_NODES;
    const int nE = in_sizes[1] / 2;  // edge_index is [2, E]
    const int* src = eidx;
    const int* dst = eidx + nE;
    const int nBk = (nN + 511) >> BSHIFT;   // 196 buckets used

    // ---- workspace layout (256B aligned)
    char* ws = (char*)d_ws;
    size_t off = 0;
    auto alloc = [&](size_t bytes) {
        char* p = ws + off;
        off += (bytes + 255) & ~(size_t)255;
        return p;
    };
    float* dinv    = (float*)alloc((size_t)nN * 4);
    int*   gcount  = (int*)  alloc(NBUCK * 4);
    int*   gbase   = (int*)  alloc(NBUCK * 4);
    int*   gcursor = (int*)  alloc(NBUCK * 4);
    int*   rowptr  = (int*)  alloc((size_t)(nN + 1) * 4);
    uint*  binned  = (uint*) alloc((size_t)nE * 4);
    int*   nbr     = (int*)  alloc((size_t)nE * 4);
    bfu*   z0      = (bfu*)  alloc((size_t)nN * 64 * 2);
    bfu*   zB      = (bfu*)  alloc((size_t)nN * 64 * 2);
    bfu*   zC      = (bfu*)  alloc((size_t)nN * 64 * 2);

    // 1. CSR build: hist -> scan -> bin -> per-bucket build (rowptr, dinv, nbr)
    hipMemsetAsync(gcount, 0, NBUCK * 4, stream);
    bucket_hist<<<640, 256, 0, stream>>>(dst, gcount, nE);
    scan_buckets<<<1, NBUCK, 0, stream>>>(gcount, gbase, gcursor);
    bin_edges<<<(nE + 4095) / 4096, 256, 0, stream>>>(src, dst, gcursor, binned, nE);
    build_csr<<<nBk, 512, 0, stream>>>(binned, gbase, gcount, rowptr, dinv, nbr, nN, nE);

    // 2. z0 = bf16(D^-1/2 x); zB = bf16(D^-1 (A+I) z0); zC = bf16(D^-1/2 (A+I) zB)
    const int n4 = nN * 16;
    scale_to_bf16<<<(n4 + 255) / 256, 256, 0, stream>>>((ushort4*)z0, (const float4*)x, dinv, n4);
    const int gBlocks = (nN + 3) / 4;
    gather_hop_bf16<2><<<gBlocks, 256, 0, stream>>>(zB, z0, nbr, rowptr, dinv, nN);
    gather_hop_bf16<1><<<gBlocks, 256, 0, stream>>>(zC, zB, nbr, rowptr, dinv, nN);

    // 3. fused MLP + log_softmax
    mlp_fused<<<(nN + 63) / 64, 256, 0, stream>>>(out, zC, W1, b1, W2, b2, nN);
}

// Round 6
// 191.702 us; speedup vs baseline: 1.5849x; 1.1154x over previous
//
#include <hip/hip_runtime.h>
#include <math.h>

#define N_NODES 100000
#define BSHIFT 9                 // 512-node buckets
#define NBUCK 256                // >= ceil(N/512)=196, pow2 for arrays

typedef unsigned short bfu;
typedef unsigned int uint;

__device__ __forceinline__ float bf2f(bfu u) {
    union { uint i; float f; } v; v.i = (uint)u << 16; return v.f;
}
__device__ __forceinline__ bfu f2bf(float f) {   // round-to-nearest-even
    union { float f_; uint i; } v; v.f_ = f;
    uint r = (v.i + 0x7FFFu + ((v.i >> 16) & 1u)) >> 16;
    return (bfu)r;
}

// ---------------------------------------------------------------- P0: bucket histogram
__global__ __launch_bounds__(256) void bucket_hist(const int* __restrict__ dst,
                                                   int* __restrict__ gcount, int nE) {
    __shared__ int h[NBUCK];
    int tid = threadIdx.x;
    h[tid] = 0;
    __syncthreads();
    for (int e = blockIdx.x * 256 + tid; e < nE; e += gridDim.x * 256)
        atomicAdd(&h[dst[e] >> BSHIFT], 1);
    __syncthreads();
    if (h[tid]) atomicAdd(&gcount[tid], h[tid]);
}

// ---------------------------------------------------------------- P0b: scan bucket counts
__global__ __launch_bounds__(NBUCK) void scan_buckets(const int* __restrict__ gcount,
                                                      int* __restrict__ gbase,
                                                      int* __restrict__ gcursor) {
    __shared__ int s[NBUCK];
    int t = threadIdx.x;
    int v = gcount[t];
    s[t] = v;
    __syncthreads();
    #pragma unroll
    for (int off = 1; off < NBUCK; off <<= 1) {
        int tv = (t >= off) ? s[t - off] : 0;
        __syncthreads();
        s[t] += tv;
        __syncthreads();
    }
    gbase[t] = s[t] - v;     // exclusive
    gcursor[t] = s[t] - v;
}

// ---------------------------------------------------------------- P1: bin edges by bucket
__global__ __launch_bounds__(256) void bin_edges(const int* __restrict__ src,
                                                 const int* __restrict__ dst,
                                                 int* __restrict__ gcursor,
                                                 uint* __restrict__ binned, int nE) {
    __shared__ int h[NBUCK];
    __shared__ int base[NBUCK];
    int tid = threadIdx.x;
    int start = blockIdx.x * 4096;
    h[tid] = 0;
    __syncthreads();
    int bkt[16], rnk[16];
    #pragma unroll
    for (int u = 0; u < 16; ++u) {
        int e = start + u * 256 + tid;
        bkt[u] = -1;
        if (e < nE) {
            int b = dst[e] >> BSHIFT;
            bkt[u] = b;
            rnk[u] = atomicAdd(&h[b], 1);
        }
    }
    __syncthreads();
    base[tid] = h[tid] ? atomicAdd(&gcursor[tid], h[tid]) : 0;
    __syncthreads();
    #pragma unroll
    for (int u = 0; u < 16; ++u) {
        int e = start + u * 256 + tid;
        if (e < nE) {
            uint pk = ((uint)(dst[e] & 511) << 17) | (uint)src[e];  // src < 2^17
            binned[base[bkt[u]] + rnk[u]] = pk;
        }
    }
}

// ---------------------------------------------------------------- P2: per-bucket CSR build
__global__ __launch_bounds__(512) void build_csr(
    const uint* __restrict__ binned, const int* __restrict__ gbase,
    const int* __restrict__ gcount, int* __restrict__ rowptr,
    float* __restrict__ dinv, int* __restrict__ nbr, int nN, int nE) {
    __shared__ int hist[512];
    __shared__ int cursor[512];
    int b = blockIdx.x, t = threadIdx.x;
    int n0 = b << BSHIFT;
    int nNodes = min(512, nN - n0);
    int base = gbase[b], cnt = gcount[b];
    hist[t] = 0;
    __syncthreads();
    for (int i = t; i < cnt; i += 512)
        atomicAdd(&hist[binned[base + i] >> 17], 1);
    __syncthreads();
    int v = hist[t];
    #pragma unroll
    for (int off = 1; off < 512; off <<= 1) {
        int tv = (t >= off) ? hist[t - off] : 0;
        __syncthreads();
        hist[t] += tv;
        __syncthreads();
    }
    int excl = hist[t] - v;
    if (t < nNodes) {
        rowptr[n0 + t] = base + excl;
        dinv[n0 + t] = rsqrtf((float)v + 1.0f);   // +1 self loop
    }
    cursor[t] = excl;
    __syncthreads();
    for (int i = t; i < cnt; i += 512) {
        uint pk = binned[base + i];
        int ld = pk >> 17;
        int pos = atomicAdd(&cursor[ld], 1);
        nbr[base + pos] = (int)(pk & 0x1FFFFu);
    }
    if (b == 0 && t == 0) rowptr[nN] = nE;
}

// ---------------------------------------------------------------- z0 = bf16(dinv * x)
__global__ void scale_to_bf16(ushort4* __restrict__ z0, const float4* __restrict__ x,
                              const float* __restrict__ dinv, int n4) {
    int t = blockIdx.x * blockDim.x + threadIdx.x;
    if (t >= n4) return;
    float w = dinv[t >> 4];
    float4 v = x[t];
    ushort4 o;
    o.x = f2bf(w * v.x); o.y = f2bf(w * v.y);
    o.z = f2bf(w * v.z); o.w = f2bf(w * v.w);
    z0[t] = o;
}

// ---------------------------------------------------------------- gather hop, 8 rows/load
// wave = 1 node; 8 groups of 8 lanes; group g owns neighbor j=beg+g+8t;
// lane (g,k) loads 16B = features [8k,8k+8) of that neighbor.
// One vector load per wave brings 8 rows (1KB) in flight.
template<int PW>
__global__ __launch_bounds__(256) void gather_hop8(
    bfu* __restrict__ out, const bfu* __restrict__ z,
    const int* __restrict__ nbr, const int* __restrict__ rowptr,
    const float* __restrict__ dinv, int nN) {
    int node = blockIdx.x * 4 + (threadIdx.x >> 6);
    if (node >= nN) return;
    int lane = threadIdx.x & 63;
    int g = lane >> 3, k = lane & 7;
    int beg = rowptr[node], end = rowptr[node + 1];

    float acc[8];
    #pragma unroll
    for (int i = 0; i < 8; ++i) acc[i] = 0.f;

    auto accum = [&](uint4 v) {
        union { uint u; float f; } t;
        t.u = v.x << 16;         acc[0] += t.f;
        t.u = v.x & 0xFFFF0000u; acc[1] += t.f;
        t.u = v.y << 16;         acc[2] += t.f;
        t.u = v.y & 0xFFFF0000u; acc[3] += t.f;
        t.u = v.z << 16;         acc[4] += t.f;
        t.u = v.z & 0xFFFF0000u; acc[5] += t.f;
        t.u = v.w << 16;         acc[6] += t.f;
        t.u = v.w & 0xFFFF0000u; acc[7] += t.f;
    };

    if (g == 0)   // self loop
        accum(reinterpret_cast<const uint4*>(z + (size_t)node * 64)[k]);
    for (int j = beg + g; j < end; j += 8)
        accum(reinterpret_cast<const uint4*>(z + (size_t)nbr[j] * 64)[k]);

    // butterfly-reduce the 8 groups (lanes with equal k)
    #pragma unroll
    for (int m = 8; m < 64; m <<= 1)
        #pragma unroll
        for (int i = 0; i < 8; ++i)
            acc[i] += __shfl_xor(acc[i], m);

    if (g == 0) {
        float di = dinv[node];
        float w = (PW == 2) ? di * di : di;
        uint4 o;
        o.x = ((uint)f2bf(acc[1] * w) << 16) | f2bf(acc[0] * w);
        o.y = ((uint)f2bf(acc[3] * w) << 16) | f2bf(acc[2] * w);
        o.z = ((uint)f2bf(acc[5] * w) << 16) | f2bf(acc[4] * w);
        o.w = ((uint)f2bf(acc[7] * w) << 16) | f2bf(acc[6] * w);
        reinterpret_cast<uint4*>(out + (size_t)node * 64)[k] = o;
    }
}

// ---------------------------------------------------------------- fused MLP + log_softmax
__global__ __launch_bounds__(256) void mlp_fused(
    float* __restrict__ out, const bfu* __restrict__ xin,
    const float* __restrict__ W1, const float* __restrict__ b1,
    const float* __restrict__ W2, const float* __restrict__ b2, int nN) {
    __shared__ float xT[64][68];    // xT[k][n]
    __shared__ float W1s[64][64];
    __shared__ float W2s[64][40];
    __shared__ float b1s[64];
    __shared__ float b2s[40];
    int tid = threadIdx.x;
    int base = blockIdx.x * 64;

    for (int i = tid; i < 64 * 64; i += 256) W1s[i >> 6][i & 63] = W1[i];
    for (int i = tid; i < 64 * 40; i += 256) W2s[i / 40][i % 40] = W2[i];
    if (tid < 64) b1s[tid] = b1[tid];
    if (tid >= 64 && tid < 104) b2s[tid - 64] = b2[tid - 64];

    {   // load 64-node bf16 tile transposed; dword = 2 features, coalesced
        const uint* xr = (const uint*)(xin + (size_t)base * 64);
        int limit = (nN - base >= 64) ? 64 * 32 : (nN - base) * 32;
        for (int i = tid; i < 64 * 32; i += 256) {
            uint v = (i < limit) ? xr[i] : 0u;
            int n = i >> 5, kk = (i & 31) * 2;
            union { uint u; float f; } lo, hi;
            lo.u = v << 16; hi.u = v & 0xFFFF0000u;
            xT[kk + 0][n] = lo.f;
            xT[kk + 1][n] = hi.f;
        }
    }
    __syncthreads();

    int h0 = (tid & 15) * 4, n0 = (tid >> 4) * 4;
    float acc[4][4];
    #pragma unroll
    for (int i = 0; i < 4; ++i)
        #pragma unroll
        for (int j = 0; j < 4; ++j) acc[i][j] = b1s[h0 + j];
    #pragma unroll 8
    for (int k = 0; k < 64; ++k) {
        float4 xv = *reinterpret_cast<const float4*>(&xT[k][n0]);
        float4 wv = *reinterpret_cast<const float4*>(&W1s[k][h0]);
        acc[0][0] = fmaf(xv.x, wv.x, acc[0][0]);
        acc[0][1] = fmaf(xv.x, wv.y, acc[0][1]);
        acc[0][2] = fmaf(xv.x, wv.z, acc[0][2]);
        acc[0][3] = fmaf(xv.x, wv.w, acc[0][3]);
        acc[1][0] = fmaf(xv.y, wv.x, acc[1][0]);
        acc[1][1] = fmaf(xv.y, wv.y, acc[1][1]);
        acc[1][2] = fmaf(xv.y, wv.z, acc[1][2]);
        acc[1][3] = fmaf(xv.y, wv.w, acc[1][3]);
        acc[2][0] = fmaf(xv.z, wv.x, acc[2][0]);
        acc[2][1] = fmaf(xv.z, wv.y, acc[2][1]);
        acc[2][2] = fmaf(xv.z, wv.z, acc[2][2]);
        acc[2][3] = fmaf(xv.z, wv.w, acc[2][3]);
        acc[3][0] = fmaf(xv.w, wv.x, acc[3][0]);
        acc[3][1] = fmaf(xv.w, wv.y, acc[3][1]);
        acc[3][2] = fmaf(xv.w, wv.z, acc[3][2]);
        acc[3][3] = fmaf(xv.w, wv.w, acc[3][3]);
    }
    __syncthreads();
    #pragma unroll
    for (int i = 0; i < 4; ++i)
        #pragma unroll
        for (int j = 0; j < 4; ++j)
            xT[h0 + j][n0 + i] = fmaxf(acc[i][j], 0.f);   // hT[hid][node]
    __syncthreads();

    int n2 = tid >> 2, q = tid & 3;
    float lg[10];
    #pragma unroll
    for (int c = 0; c < 10; ++c) lg[c] = b2s[q * 10 + c];
    #pragma unroll 4
    for (int k = 0; k < 64; ++k) {
        float hv = xT[k][n2];
        #pragma unroll
        for (int c = 0; c < 10; ++c)
            lg[c] = fmaf(hv, W2s[k][q * 10 + c], lg[c]);
    }
    float m = lg[0];
    #pragma unroll
    for (int c = 1; c < 10; ++c) m = fmaxf(m, lg[c]);
    m = fmaxf(m, __shfl_xor(m, 1));
    m = fmaxf(m, __shfl_xor(m, 2));
    float s = 0.f;
    #pragma unroll
    for (int c = 0; c < 10; ++c) s += expf(lg[c] - m);
    s += __shfl_xor(s, 1);
    s += __shfl_xor(s, 2);
    float lse = m + logf(s);
    int gn = base + n2;
    if (gn < nN) {
        #pragma unroll
        for (int c = 0; c < 10; ++c)
            out[(size_t)gn * 40 + q * 10 + c] = lg[c] - lse;
    }
}

extern "C" void kernel_launch(void* const* d_in, const int* in_sizes, int n_in,
                              void* d_out, int out_size, void* d_ws, size_t ws_size,
                              hipStream_t stream) {
    const float* x   = (const float*)d_in[0];
    const int* eidx  = (const int*)d_in[1];
    const float* W1  = (const float*)d_in[2];
    const float* b1  = (const float*)d_in[3];
    const float* W2  = (const float*)d_in[4];
    const float* b2  = (const float*)d_in[5];
    float* out = (float*)d_out;

    const int nN = N_NODES;
    const int nE = in_sizes[1] / 2;  // edge_index is [2, E]
    const int* src = eidx;
    const int* dst = eidx + nE;
    const int nBk = (nN + 511) >> BSHIFT;   // 196 buckets used

    // ---- workspace layout (256B aligned)
    char* ws = (char*)d_ws;
    size_t off = 0;
    auto alloc = [&](size_t bytes) {
        char* p = ws + off;
        off += (bytes + 255) & ~(size_t)255;
        return p;
    };
    float* dinv    = (float*)alloc((size_t)nN * 4);
    int*   gcount  = (int*)  alloc(NBUCK * 4);
    int*   gbase   = (int*)  alloc(NBUCK * 4);
    int*   gcursor = (int*)  alloc(NBUCK * 4);
    int*   rowptr  = (int*)  alloc((size_t)(nN + 1) * 4);
    uint*  binned  = (uint*) alloc((size_t)nE * 4);
    int*   nbr     = (int*)  alloc((size_t)nE * 4);
    bfu*   z0      = (bfu*)  alloc((size_t)nN * 64 * 2);
    bfu*   zB      = (bfu*)  alloc((size_t)nN * 64 * 2);
    bfu*   zC      = (bfu*)  alloc((size_t)nN * 64 * 2);

    // 1. CSR build: hist -> scan -> bin -> per-bucket build (rowptr, dinv, nbr)
    hipMemsetAsync(gcount, 0, NBUCK * 4, stream);
    bucket_hist<<<640, 256, 0, stream>>>(dst, gcount, nE);
    scan_buckets<<<1, NBUCK, 0, stream>>>(gcount, gbase, gcursor);
    bin_edges<<<(nE + 4095) / 4096, 256, 0, stream>>>(src, dst, gcursor, binned, nE);
    build_csr<<<nBk, 512, 0, stream>>>(binned, gbase, gcount, rowptr, dinv, nbr, nN, nE);

    // 2. z0 = bf16(D^-1/2 x); zB = bf16(D^-1 (A+I) z0); zC = bf16(D^-1/2 (A+I) zB)
    const int n4 = nN * 16;
    scale_to_bf16<<<(n4 + 255) / 256, 256, 0, stream>>>((ushort4*)z0, (const float4*)x, dinv, n4);
    const int gBlocks = (nN + 3) / 4;
    gather_hop8<2><<<gBlocks, 256, 0, stream>>>(zB, z0, nbr, rowptr, dinv, nN);
    gather_hop8<1><<<gBlocks, 256, 0, stream>>>(zC, zB, nbr, rowptr, dinv, nN);

    // 3. fused MLP + log_softmax
    mlp_fused<<<(nN + 63) / 64, 256, 0, stream>>>(out, zC, W1, b1, W2, b2, nN);
}

// Round 7
// 165.993 us; speedup vs baseline: 1.8304x; 1.1549x over previous
//
#include <hip/hip_runtime.h>
#include <math.h>

#define N_NODES 100000
#define BSHIFT 9                 // 512-node buckets
#define NBUCK 256                // >= ceil(N/512)=196, pow2 for arrays

typedef unsigned short bfu;
typedef unsigned int uint;
typedef __attribute__((ext_vector_type(8))) short short8v;   // 8 bf16 = 4 VGPRs
typedef __attribute__((ext_vector_type(4))) float f32x4;

__device__ __forceinline__ float bf2f(bfu u) {
    union { uint i; float f; } v; v.i = (uint)u << 16; return v.f;
}
__device__ __forceinline__ bfu f2bf(float f) {   // round-to-nearest-even
    union { float f_; uint i; } v; v.f_ = f;
    uint r = (v.i + 0x7FFFu + ((v.i >> 16) & 1u)) >> 16;
    return (bfu)r;
}

// ---------------------------------------------------------------- P0: bucket histogram
__global__ __launch_bounds__(256) void bucket_hist(const int* __restrict__ dst,
                                                   int* __restrict__ gcount, int nE) {
    __shared__ int h[NBUCK];
    int tid = threadIdx.x;
    h[tid] = 0;
    __syncthreads();
    for (int e = blockIdx.x * 256 + tid; e < nE; e += gridDim.x * 256)
        atomicAdd(&h[dst[e] >> BSHIFT], 1);
    __syncthreads();
    if (h[tid]) atomicAdd(&gcount[tid], h[tid]);
}

// ---------------------------------------------------------------- P0b: scan bucket counts
__global__ __launch_bounds__(NBUCK) void scan_buckets(const int* __restrict__ gcount,
                                                      int* __restrict__ gbase,
                                                      int* __restrict__ gcursor) {
    __shared__ int s[NBUCK];
    int t = threadIdx.x;
    int v = gcount[t];
    s[t] = v;
    __syncthreads();
    #pragma unroll
    for (int off = 1; off < NBUCK; off <<= 1) {
        int tv = (t >= off) ? s[t - off] : 0;
        __syncthreads();
        s[t] += tv;
        __syncthreads();
    }
    gbase[t] = s[t] - v;     // exclusive
    gcursor[t] = s[t] - v;
}

// ---------------------------------------------------------------- P1: bin edges by bucket
__global__ __launch_bounds__(256) void bin_edges(const int* __restrict__ src,
                                                 const int* __restrict__ dst,
                                                 int* __restrict__ gcursor,
                                                 uint* __restrict__ binned, int nE) {
    __shared__ int h[NBUCK];
    __shared__ int base[NBUCK];
    int tid = threadIdx.x;
    int start = blockIdx.x * 4096;
    h[tid] = 0;
    __syncthreads();
    int bkt[16], rnk[16];
    #pragma unroll
    for (int u = 0; u < 16; ++u) {
        int e = start + u * 256 + tid;
        bkt[u] = -1;
        if (e < nE) {
            int b = dst[e] >> BSHIFT;
            bkt[u] = b;
            rnk[u] = atomicAdd(&h[b], 1);
        }
    }
    __syncthreads();
    base[tid] = h[tid] ? atomicAdd(&gcursor[tid], h[tid]) : 0;
    __syncthreads();
    #pragma unroll
    for (int u = 0; u < 16; ++u) {
        int e = start + u * 256 + tid;
        if (e < nE) {
            uint pk = ((uint)(dst[e] & 511) << 17) | (uint)src[e];  // src < 2^17
            binned[base[bkt[u]] + rnk[u]] = pk;
        }
    }
}

// ---------------------------------------------------------------- P2: per-bucket CSR build
__global__ __launch_bounds__(512) void build_csr(
    const uint* __restrict__ binned, const int* __restrict__ gbase,
    const int* __restrict__ gcount, int* __restrict__ rowptr,
    float* __restrict__ dinv, int* __restrict__ nbr, int nN, int nE) {
    __shared__ int hist[512];
    __shared__ int cursor[512];
    int b = blockIdx.x, t = threadIdx.x;
    int n0 = b << BSHIFT;
    int nNodes = min(512, nN - n0);
    int base = gbase[b], cnt = gcount[b];
    hist[t] = 0;
    __syncthreads();
    for (int i = t; i < cnt; i += 512)
        atomicAdd(&hist[binned[base + i] >> 17], 1);
    __syncthreads();
    int v = hist[t];
    #pragma unroll
    for (int off = 1; off < 512; off <<= 1) {
        int tv = (t >= off) ? hist[t - off] : 0;
        __syncthreads();
        hist[t] += tv;
        __syncthreads();
    }
    int excl = hist[t] - v;
    if (t < nNodes) {
        rowptr[n0 + t] = base + excl;
        dinv[n0 + t] = rsqrtf((float)v + 1.0f);   // +1 self loop
    }
    cursor[t] = excl;
    __syncthreads();
    for (int i = t; i < cnt; i += 512) {
        uint pk = binned[base + i];
        int ld = pk >> 17;
        int pos = atomicAdd(&cursor[ld], 1);
        nbr[base + pos] = (int)(pk & 0x1FFFFu);
    }
    if (b == 0 && t == 0) rowptr[nN] = nE;
}

// ---------------------------------------------------------------- z0 = bf16(dinv * x)
__global__ void scale_to_bf16(ushort4* __restrict__ z0, const float4* __restrict__ x,
                              const float* __restrict__ dinv, int n4) {
    int t = blockIdx.x * blockDim.x + threadIdx.x;
    if (t >= n4) return;
    float w = dinv[t >> 4];
    float4 v = x[t];
    ushort4 o;
    o.x = f2bf(w * v.x); o.y = f2bf(w * v.y);
    o.z = f2bf(w * v.z); o.w = f2bf(w * v.w);
    z0[t] = o;
}

// ---------------------------------------------------------------- gather hop, 8 rows/load
template<int PW>
__global__ __launch_bounds__(256) void gather_hop8(
    bfu* __restrict__ out, const bfu* __restrict__ z,
    const int* __restrict__ nbr, const int* __restrict__ rowptr,
    const float* __restrict__ dinv, int nN) {
    int node = blockIdx.x * 4 + (threadIdx.x >> 6);
    if (node >= nN) return;
    int lane = threadIdx.x & 63;
    int g = lane >> 3, k = lane & 7;
    int beg = rowptr[node], end = rowptr[node + 1];

    float acc[8];
    #pragma unroll
    for (int i = 0; i < 8; ++i) acc[i] = 0.f;

    auto accum = [&](uint4 v) {
        union { uint u; float f; } t;
        t.u = v.x << 16;         acc[0] += t.f;
        t.u = v.x & 0xFFFF0000u; acc[1] += t.f;
        t.u = v.y << 16;         acc[2] += t.f;
        t.u = v.y & 0xFFFF0000u; acc[3] += t.f;
        t.u = v.z << 16;         acc[4] += t.f;
        t.u = v.z & 0xFFFF0000u; acc[5] += t.f;
        t.u = v.w << 16;         acc[6] += t.f;
        t.u = v.w & 0xFFFF0000u; acc[7] += t.f;
    };

    if (g == 0)   // self loop
        accum(reinterpret_cast<const uint4*>(z + (size_t)node * 64)[k]);
    for (int j = beg + g; j < end; j += 8)
        accum(reinterpret_cast<const uint4*>(z + (size_t)nbr[j] * 64)[k]);

    #pragma unroll
    for (int m = 8; m < 64; m <<= 1)
        #pragma unroll
        for (int i = 0; i < 8; ++i)
            acc[i] += __shfl_xor(acc[i], m);

    if (g == 0) {
        float di = dinv[node];
        float w = (PW == 2) ? di * di : di;
        uint4 o;
        o.x = ((uint)f2bf(acc[1] * w) << 16) | f2bf(acc[0] * w);
        o.y = ((uint)f2bf(acc[3] * w) << 16) | f2bf(acc[2] * w);
        o.z = ((uint)f2bf(acc[5] * w) << 16) | f2bf(acc[4] * w);
        o.w = ((uint)f2bf(acc[7] * w) << 16) | f2bf(acc[6] * w);
        reinterpret_cast<uint4*>(out + (size_t)node * 64)[k] = o;
    }
}

// ---------------------------------------------------------------- MFMA MLP + log_softmax
// block = 256 threads = 4 waves; wave = 16 nodes (M-tile).
// stage1: h = relu(zC @ W1 + b1)  via 8x mfma_f32_16x16x32_bf16 (K=64, N=64)
// stage2: logits = h @ W2 + b2    via 6x mfma (N=48, cols 40..47 zero-padded)
// LDS stride 72 shorts (144B) => bank = 4*row mod 32 => worst 2-way (free).
__global__ __launch_bounds__(256) void mlp_mfma(
    float* __restrict__ out, const bfu* __restrict__ zC,
    const float* __restrict__ W1, const float* __restrict__ b1,
    const float* __restrict__ W2, const float* __restrict__ b2, int nN) {
    __shared__ short w1t[64 * 72];   // w1t[n][k] bf16
    __shared__ short w2t[48 * 72];   // w2t[n][k] bf16, n 40..47 = 0
    __shared__ short hlds[64 * 72];  // h[node][hid] bf16
    __shared__ float b1s[64];
    __shared__ float b2s[48];

    int tid = threadIdx.x;
    // --- stage weights (transposed) into LDS
    for (int i = tid; i < 64 * 64; i += 256) {       // read W1 coalesced
        int k = i >> 6, n = i & 63;
        w1t[n * 72 + k] = (short)f2bf(W1[i]);
    }
    for (int i = tid; i < 48 * 64; i += 256) {       // read W2 row-chunks
        int k = i / 48, n = i % 48;
        w2t[n * 72 + k] = (short)(n < 40 ? f2bf(W2[k * 40 + n]) : 0);
    }
    if (tid < 64) b1s[tid] = b1[tid];
    if (tid >= 64 && tid < 112) b2s[tid - 64] = (tid - 64 < 40) ? b2[tid - 64] : 0.f;

    int wv = tid >> 6, l = tid & 63;
    int li = l & 15, kg = l >> 4;                    // lane-in-16, k-group 0..3
    int nodebase = blockIdx.x * 64 + wv * 16;
    int nclamp = min(nodebase + li, nN - 1);

    // --- A fragments straight from global zC (row = li, k = kg*8+j / +32)
    const short8v* zr = (const short8v*)(zC + (size_t)nclamp * 64);
    short8v a0 = zr[kg];
    short8v a1 = zr[kg + 4];
    __syncthreads();

    // --- stage 1: 4 N-tiles x 2 K-steps
    f32x4 acc[4];
    #pragma unroll
    for (int nt = 0; nt < 4; ++nt) {
        f32x4 c = {0.f, 0.f, 0.f, 0.f};
        short8v b0 = *(const short8v*)&w1t[(nt * 16 + li) * 72 + kg * 8];
        short8v b1f = *(const short8v*)&w1t[(nt * 16 + li) * 72 + 32 + kg * 8];
        c = __builtin_amdgcn_mfma_f32_16x16x32_bf16(a0, b0, c, 0, 0, 0);
        c = __builtin_amdgcn_mfma_f32_16x16x32_bf16(a1, b1f, c, 0, 0, 0);
        acc[nt] = c;
    }
    // bias + relu -> hlds[node][hid]  (row = kg*4+r, col = nt*16+li)
    #pragma unroll
    for (int nt = 0; nt < 4; ++nt) {
        float bb = b1s[nt * 16 + li];
        #pragma unroll
        for (int r = 0; r < 4; ++r) {
            float v = fmaxf(acc[nt][r] + bb, 0.f);
            hlds[(wv * 16 + kg * 4 + r) * 72 + nt * 16 + li] = (short)f2bf(v);
        }
    }
    __syncthreads();

    // --- stage 2: A from hlds, 3 N-tiles x 2 K-steps
    const short8v* hp = (const short8v*)&hlds[(wv * 16 + li) * 72];
    short8v ha0 = hp[kg];          // k = kg*8
    short8v ha1 = hp[kg + 4];      // k = 32 + kg*8
    f32x4 acc2[3];
    #pragma unroll
    for (int nt = 0; nt < 3; ++nt) {
        f32x4 c = {0.f, 0.f, 0.f, 0.f};
        short8v b0 = *(const short8v*)&w2t[(nt * 16 + li) * 72 + kg * 8];
        short8v b1f = *(const short8v*)&w2t[(nt * 16 + li) * 72 + 32 + kg * 8];
        c = __builtin_amdgcn_mfma_f32_16x16x32_bf16(ha0, b0, c, 0, 0, 0);
        c = __builtin_amdgcn_mfma_f32_16x16x32_bf16(ha1, b1f, c, 0, 0, 0);
        acc2[nt] = c;
    }

    // --- log_softmax: node = nodebase + kg*4 + r; cols nt*16+li (valid < 40)
    float lg[3][4];
    #pragma unroll
    for (int nt = 0; nt < 3; ++nt) {
        float bb = b2s[nt * 16 + li];
        #pragma unroll
        for (int r = 0; r < 4; ++r) lg[nt][r] = acc2[nt][r] + bb;
    }
    bool v2 = (li < 8);   // tile 2 valid cols 32..39
    float mx[4], sm[4];
    #pragma unroll
    for (int r = 0; r < 4; ++r) {
        float m = fmaxf(lg[0][r], lg[1][r]);
        if (v2) m = fmaxf(m, lg[2][r]);
        mx[r] = m;
    }
    #pragma unroll
    for (int off = 1; off < 16; off <<= 1)
        #pragma unroll
        for (int r = 0; r < 4; ++r)
            mx[r] = fmaxf(mx[r], __shfl_xor(mx[r], off));
    #pragma unroll
    for (int r = 0; r < 4; ++r) {
        float s = expf(lg[0][r] - mx[r]) + expf(lg[1][r] - mx[r]);
        if (v2) s += expf(lg[2][r] - mx[r]);
        sm[r] = s;
    }
    #pragma unroll
    for (int off = 1; off < 16; off <<= 1)
        #pragma unroll
        for (int r = 0; r < 4; ++r)
            sm[r] += __shfl_xor(sm[r], off);

    int nb2 = nodebase + kg * 4;
    #pragma unroll
    for (int r = 0; r < 4; ++r) {
        int nd = nb2 + r;
        if (nd < nN) {
            float lse = mx[r] + logf(sm[r]);
            out[(size_t)nd * 40 + li]      = lg[0][r] - lse;
            out[(size_t)nd * 40 + 16 + li] = lg[1][r] - lse;
            if (v2) out[(size_t)nd * 40 + 32 + li] = lg[2][r] - lse;
        }
    }
}

extern "C" void kernel_launch(void* const* d_in, const int* in_sizes, int n_in,
                              void* d_out, int out_size, void* d_ws, size_t ws_size,
                              hipStream_t stream) {
    const float* x   = (const float*)d_in[0];
    const int* eidx  = (const int*)d_in[1];
    const float* W1  = (const float*)d_in[2];
    const float* b1  = (const float*)d_in[3];
    const float* W2  = (const float*)d_in[4];
    const float* b2  = (const float*)d_in[5];
    float* out = (float*)d_out;

    const int nN = N_NODES;
    const int nE = in_sizes[1] / 2;  // edge_index is [2, E]
    const int* src = eidx;
    const int* dst = eidx + nE;
    const int nBk = (nN + 511) >> BSHIFT;   // 196 buckets used

    // ---- workspace layout (256B aligned)
    char* ws = (char*)d_ws;
    size_t off = 0;
    auto alloc = [&](size_t bytes) {
        char* p = ws + off;
        off += (bytes + 255) & ~(size_t)255;
        return p;
    };
    float* dinv    = (float*)alloc((size_t)nN * 4);
    int*   gcount  = (int*)  alloc(NBUCK * 4);
    int*   gbase   = (int*)  alloc(NBUCK * 4);
    int*   gcursor = (int*)  alloc(NBUCK * 4);
    int*   rowptr  = (int*)  alloc((size_t)(nN + 1) * 4);
    uint*  binned  = (uint*) alloc((size_t)nE * 4);
    int*   nbr     = (int*)  alloc((size_t)nE * 4);
    bfu*   z0      = (bfu*)  alloc((size_t)nN * 64 * 2);
    bfu*   zB      = (bfu*)  alloc((size_t)nN * 64 * 2);
    bfu*   zC      = (bfu*)  alloc((size_t)nN * 64 * 2);

    // 1. CSR build: hist -> scan -> bin -> per-bucket build (rowptr, dinv, nbr)
    hipMemsetAsync(gcount, 0, NBUCK * 4, stream);
    bucket_hist<<<640, 256, 0, stream>>>(dst, gcount, nE);
    scan_buckets<<<1, NBUCK, 0, stream>>>(gcount, gbase, gcursor);
    bin_edges<<<(nE + 4095) / 4096, 256, 0, stream>>>(src, dst, gcursor, binned, nE);
    build_csr<<<nBk, 512, 0, stream>>>(binned, gbase, gcount, rowptr, dinv, nbr, nN, nE);

    // 2. z0 = bf16(D^-1/2 x); zB = bf16(D^-1 (A+I) z0); zC = bf16(D^-1/2 (A+I) zB)
    const int n4 = nN * 16;
    scale_to_bf16<<<(n4 + 255) / 256, 256, 0, stream>>>((ushort4*)z0, (const float4*)x, dinv, n4);
    const int gBlocks = (nN + 3) / 4;
    gather_hop8<2><<<gBlocks, 256, 0, stream>>>(zB, z0, nbr, rowptr, dinv, nN);
    gather_hop8<1><<<gBlocks, 256, 0, stream>>>(zC, zB, nbr, rowptr, dinv, nN);

    // 3. MFMA MLP + log_softmax
    mlp_mfma<<<(nN + 63) / 64, 256, 0, stream>>>(out, zC, W1, b1, W2, b2, nN);
}

// Round 8
// 162.168 us; speedup vs baseline: 1.8736x; 1.0236x over previous
//
#include <hip/hip_runtime.h>
#include <math.h>

#define N_NODES 100000
#define BSHIFT 9                 // 512-node buckets
#define NBUCK 256                // >= ceil(N/512)=196, pow2 for arrays

typedef unsigned short bfu;
typedef unsigned int uint;
typedef __attribute__((ext_vector_type(8))) short short8v;   // 8 bf16 = 4 VGPRs
typedef __attribute__((ext_vector_type(4))) float f32x4;

__device__ __forceinline__ float bf2f(bfu u) {
    union { uint i; float f; } v; v.i = (uint)u << 16; return v.f;
}
__device__ __forceinline__ bfu f2bf(float f) {   // round-to-nearest-even
    union { float f_; uint i; } v; v.f_ = f;
    uint r = (v.i + 0x7FFFu + ((v.i >> 16) & 1u)) >> 16;
    return (bfu)r;
}

// ---------------------------------------------------------------- P0: bucket histogram
__global__ __launch_bounds__(256) void bucket_hist(const int* __restrict__ dst,
                                                   int* __restrict__ gcount, int nE) {
    __shared__ int h[NBUCK];
    int tid = threadIdx.x;
    h[tid] = 0;
    __syncthreads();
    for (int e = blockIdx.x * 256 + tid; e < nE; e += gridDim.x * 256)
        atomicAdd(&h[dst[e] >> BSHIFT], 1);
    __syncthreads();
    if (h[tid]) atomicAdd(&gcount[tid], h[tid]);
}

// ---------------------------------------------------------------- P0b: scan bucket counts
__global__ __launch_bounds__(NBUCK) void scan_buckets(const int* __restrict__ gcount,
                                                      int* __restrict__ gbase,
                                                      int* __restrict__ gcursor) {
    __shared__ int s[NBUCK];
    int t = threadIdx.x;
    int v = gcount[t];
    s[t] = v;
    __syncthreads();
    #pragma unroll
    for (int off = 1; off < NBUCK; off <<= 1) {
        int tv = (t >= off) ? s[t - off] : 0;
        __syncthreads();
        s[t] += tv;
        __syncthreads();
    }
    gbase[t] = s[t] - v;     // exclusive
    gcursor[t] = s[t] - v;
}

// ---------------------------------------------------------------- P1: bin edges by bucket
__global__ __launch_bounds__(256) void bin_edges(const int* __restrict__ src,
                                                 const int* __restrict__ dst,
                                                 int* __restrict__ gcursor,
                                                 uint* __restrict__ binned, int nE) {
    __shared__ int h[NBUCK];
    __shared__ int base[NBUCK];
    int tid = threadIdx.x;
    int start = blockIdx.x * 4096;
    h[tid] = 0;
    __syncthreads();
    int bkt[16], rnk[16];
    #pragma unroll
    for (int u = 0; u < 16; ++u) {
        int e = start + u * 256 + tid;
        bkt[u] = -1;
        if (e < nE) {
            int b = dst[e] >> BSHIFT;
            bkt[u] = b;
            rnk[u] = atomicAdd(&h[b], 1);
        }
    }
    __syncthreads();
    base[tid] = h[tid] ? atomicAdd(&gcursor[tid], h[tid]) : 0;
    __syncthreads();
    #pragma unroll
    for (int u = 0; u < 16; ++u) {
        int e = start + u * 256 + tid;
        if (e < nE) {
            uint pk = ((uint)(dst[e] & 511) << 17) | (uint)src[e];  // src < 2^17
            binned[base[bkt[u]] + rnk[u]] = pk;
        }
    }
}

// ---------------------------------------------------------------- P2: per-bucket CSR build
// rowptr + dinv + nbr scatter, then epilogue: z0 = bf16(dinv * x) for this
// bucket's nodes (coalesced float4->ushort4, dinv from LDS).
__global__ __launch_bounds__(512) void build_csr(
    const uint* __restrict__ binned, const int* __restrict__ gbase,
    const int* __restrict__ gcount, int* __restrict__ rowptr,
    float* __restrict__ dinv, int* __restrict__ nbr,
    const float4* __restrict__ x, ushort4* __restrict__ z0, int nN, int nE) {
    __shared__ int hist[512];
    __shared__ int cursor[512];
    int b = blockIdx.x, t = threadIdx.x;
    int n0 = b << BSHIFT;
    int nNodes = min(512, nN - n0);
    int base = gbase[b], cnt = gcount[b];
    hist[t] = 0;
    __syncthreads();
    for (int i = t; i < cnt; i += 512)
        atomicAdd(&hist[binned[base + i] >> 17], 1);
    __syncthreads();
    int v = hist[t];
    #pragma unroll
    for (int off = 1; off < 512; off <<= 1) {
        int tv = (t >= off) ? hist[t - off] : 0;
        __syncthreads();
        hist[t] += tv;
        __syncthreads();
    }
    int excl = hist[t] - v;
    float dv = rsqrtf((float)v + 1.0f);           // +1 self loop
    if (t < nNodes) {
        rowptr[n0 + t] = base + excl;
        dinv[n0 + t] = dv;
    }
    cursor[t] = excl;
    ((float*)hist)[t] = dv;                        // hist reused as dinv cache
    __syncthreads();
    for (int i = t; i < cnt; i += 512) {
        uint pk = binned[base + i];
        int ld = pk >> 17;
        int pos = atomicAdd(&cursor[ld], 1);
        nbr[base + pos] = (int)(pk & 0x1FFFFu);
    }
    // epilogue: z0 rows for this bucket (independent of scatter above)
    const float4* xr = x + (size_t)n0 * 16;
    ushort4* zr = z0 + (size_t)n0 * 16;
    int totalF4 = nNodes * 16;
    for (int i = t; i < totalF4; i += 512) {
        float w = ((float*)hist)[i >> 4];
        float4 vv = xr[i];
        ushort4 o;
        o.x = f2bf(w * vv.x); o.y = f2bf(w * vv.y);
        o.z = f2bf(w * vv.z); o.w = f2bf(w * vv.w);
        zr[i] = o;
    }
    if (b == 0 && t == 0) rowptr[nN] = nE;
}

// ---------------------------------------------------------------- gather hop, 8 rows/load
// wave = 1 node; 8 groups of 8 lanes; unroll-2 over the 8-stride keeps two
// independent nbr->row chains (16 rows) in flight per wave.
template<int PW>
__global__ __launch_bounds__(256, 8) void gather_hop8(
    bfu* __restrict__ out, const bfu* __restrict__ z,
    const int* __restrict__ nbr, const int* __restrict__ rowptr,
    const float* __restrict__ dinv, int nN) {
    int node = blockIdx.x * 4 + (threadIdx.x >> 6);
    if (node >= nN) return;
    int lane = threadIdx.x & 63;
    int g = lane >> 3, k = lane & 7;
    int beg = rowptr[node], end = rowptr[node + 1];

    float acc[8];
    #pragma unroll
    for (int i = 0; i < 8; ++i) acc[i] = 0.f;

    auto rowload = [&](int s) -> uint4 {
        return reinterpret_cast<const uint4*>(z + (size_t)s * 64)[k];
    };
    auto accum = [&](uint4 v) {
        union { uint u; float f; } t;
        t.u = v.x << 16;         acc[0] += t.f;
        t.u = v.x & 0xFFFF0000u; acc[1] += t.f;
        t.u = v.y << 16;         acc[2] += t.f;
        t.u = v.y & 0xFFFF0000u; acc[3] += t.f;
        t.u = v.z << 16;         acc[4] += t.f;
        t.u = v.z & 0xFFFF0000u; acc[5] += t.f;
        t.u = v.w << 16;         acc[6] += t.f;
        t.u = v.w & 0xFFFF0000u; acc[7] += t.f;
    };

    if (g == 0)   // self loop
        accum(rowload(node));
    int j = beg + g;
    for (; j + 8 < end; j += 16) {       // both j and j+8 valid
        int i0 = nbr[j], i1 = nbr[j + 8];
        uint4 v0 = rowload(i0);
        uint4 v1 = rowload(i1);
        accum(v0);
        accum(v1);
    }
    if (j < end)
        accum(rowload(nbr[j]));

    #pragma unroll
    for (int m = 8; m < 64; m <<= 1)
        #pragma unroll
        for (int i = 0; i < 8; ++i)
            acc[i] += __shfl_xor(acc[i], m);

    if (g == 0) {
        float di = dinv[node];
        float w = (PW == 2) ? di * di : di;
        uint4 o;
        o.x = ((uint)f2bf(acc[1] * w) << 16) | f2bf(acc[0] * w);
        o.y = ((uint)f2bf(acc[3] * w) << 16) | f2bf(acc[2] * w);
        o.z = ((uint)f2bf(acc[5] * w) << 16) | f2bf(acc[4] * w);
        o.w = ((uint)f2bf(acc[7] * w) << 16) | f2bf(acc[6] * w);
        reinterpret_cast<uint4*>(out + (size_t)node * 64)[k] = o;
    }
}

// ---------------------------------------------------------------- MFMA MLP + log_softmax
// block = 256 threads = 4 waves; wave = 16 nodes (M-tile).
// stage1: h = relu(zC @ W1 + b1)  via 8x mfma_f32_16x16x32_bf16 (K=64, N=64)
// stage2: logits = h @ W2 + b2    via 6x mfma (N=48, cols 40..47 zero-padded)
// LDS stride 72 shorts (144B) => bank = 4*row mod 32 => worst 2-way (free).
__global__ __launch_bounds__(256) void mlp_mfma(
    float* __restrict__ out, const bfu* __restrict__ zC,
    const float* __restrict__ W1, const float* __restrict__ b1,
    const float* __restrict__ W2, const float* __restrict__ b2, int nN) {
    __shared__ short w1t[64 * 72];   // w1t[n][k] bf16
    __shared__ short w2t[48 * 72];   // w2t[n][k] bf16, n 40..47 = 0
    __shared__ short hlds[64 * 72];  // h[node][hid] bf16
    __shared__ float b1s[64];
    __shared__ float b2s[48];

    int tid = threadIdx.x;
    for (int i = tid; i < 64 * 64; i += 256) {       // read W1 coalesced
        int k = i >> 6, n = i & 63;
        w1t[n * 72 + k] = (short)f2bf(W1[i]);
    }
    for (int i = tid; i < 48 * 64; i += 256) {       // read W2 row-chunks
        int k = i / 48, n = i % 48;
        w2t[n * 72 + k] = (short)(n < 40 ? f2bf(W2[k * 40 + n]) : 0);
    }
    if (tid < 64) b1s[tid] = b1[tid];
    if (tid >= 64 && tid < 112) b2s[tid - 64] = (tid - 64 < 40) ? b2[tid - 64] : 0.f;

    int wv = tid >> 6, l = tid & 63;
    int li = l & 15, kg = l >> 4;                    // lane-in-16, k-group 0..3
    int nodebase = blockIdx.x * 64 + wv * 16;
    int nclamp = min(nodebase + li, nN - 1);

    const short8v* zr = (const short8v*)(zC + (size_t)nclamp * 64);
    short8v a0 = zr[kg];
    short8v a1 = zr[kg + 4];
    __syncthreads();

    f32x4 acc[4];
    #pragma unroll
    for (int nt = 0; nt < 4; ++nt) {
        f32x4 c = {0.f, 0.f, 0.f, 0.f};
        short8v b0 = *(const short8v*)&w1t[(nt * 16 + li) * 72 + kg * 8];
        short8v b1f = *(const short8v*)&w1t[(nt * 16 + li) * 72 + 32 + kg * 8];
        c = __builtin_amdgcn_mfma_f32_16x16x32_bf16(a0, b0, c, 0, 0, 0);
        c = __builtin_amdgcn_mfma_f32_16x16x32_bf16(a1, b1f, c, 0, 0, 0);
        acc[nt] = c;
    }
    #pragma unroll
    for (int nt = 0; nt < 4; ++nt) {
        float bb = b1s[nt * 16 + li];
        #pragma unroll
        for (int r = 0; r < 4; ++r) {
            float v = fmaxf(acc[nt][r] + bb, 0.f);
            hlds[(wv * 16 + kg * 4 + r) * 72 + nt * 16 + li] = (short)f2bf(v);
        }
    }
    __syncthreads();

    const short8v* hp = (const short8v*)&hlds[(wv * 16 + li) * 72];
    short8v ha0 = hp[kg];
    short8v ha1 = hp[kg + 4];
    f32x4 acc2[3];
    #pragma unroll
    for (int nt = 0; nt < 3; ++nt) {
        f32x4 c = {0.f, 0.f, 0.f, 0.f};
        short8v b0 = *(const short8v*)&w2t[(nt * 16 + li) * 72 + kg * 8];
        short8v b1f = *(const short8v*)&w2t[(nt * 16 + li) * 72 + 32 + kg * 8];
        c = __builtin_amdgcn_mfma_f32_16x16x32_bf16(ha0, b0, c, 0, 0, 0);
        c = __builtin_amdgcn_mfma_f32_16x16x32_bf16(ha1, b1f, c, 0, 0, 0);
        acc2[nt] = c;
    }

    float lg[3][4];
    #pragma unroll
    for (int nt = 0; nt < 3; ++nt) {
        float bb = b2s[nt * 16 + li];
        #pragma unroll
        for (int r = 0; r < 4; ++r) lg[nt][r] = acc2[nt][r] + bb;
    }
    bool v2 = (li < 8);   // tile 2 valid cols 32..39
    float mx[4], sm[4];
    #pragma unroll
    for (int r = 0; r < 4; ++r) {
        float m = fmaxf(lg[0][r], lg[1][r]);
        if (v2) m = fmaxf(m, lg[2][r]);
        mx[r] = m;
    }
    #pragma unroll
    for (int off = 1; off < 16; off <<= 1)
        #pragma unroll
        for (int r = 0; r < 4; ++r)
            mx[r] = fmaxf(mx[r], __shfl_xor(mx[r], off));
    #pragma unroll
    for (int r = 0; r < 4; ++r) {
        float s = expf(lg[0][r] - mx[r]) + expf(lg[1][r] - mx[r]);
        if (v2) s += expf(lg[2][r] - mx[r]);
        sm[r] = s;
    }
    #pragma unroll
    for (int off = 1; off < 16; off <<= 1)
        #pragma unroll
        for (int r = 0; r < 4; ++r)
            sm[r] += __shfl_xor(sm[r], off);

    int nb2 = nodebase + kg * 4;
    #pragma unroll
    for (int r = 0; r < 4; ++r) {
        int nd = nb2 + r;
        if (nd < nN) {
            float lse = mx[r] + logf(sm[r]);
            out[(size_t)nd * 40 + li]      = lg[0][r] - lse;
            out[(size_t)nd * 40 + 16 + li] = lg[1][r] - lse;
            if (v2) out[(size_t)nd * 40 + 32 + li] = lg[2][r] - lse;
        }
    }
}

extern "C" void kernel_launch(void* const* d_in, const int* in_sizes, int n_in,
                              void* d_out, int out_size, void* d_ws, size_t ws_size,
                              hipStream_t stream) {
    const float* x   = (const float*)d_in[0];
    const int* eidx  = (const int*)d_in[1];
    const float* W1  = (const float*)d_in[2];
    const float* b1  = (const float*)d_in[3];
    const float* W2  = (const float*)d_in[4];
    const float* b2  = (const float*)d_in[5];
    float* out = (float*)d_out;

    const int nN = N_NODES;
    const int nE = in_sizes[1] / 2;  // edge_index is [2, E]
    const int* src = eidx;
    const int* dst = eidx + nE;
    const int nBk = (nN + 511) >> BSHIFT;   // 196 buckets used

    // ---- workspace layout (256B aligned)
    char* ws = (char*)d_ws;
    size_t off = 0;
    auto alloc = [&](size_t bytes) {
        char* p = ws + off;
        off += (bytes + 255) & ~(size_t)255;
        return p;
    };
    float* dinv    = (float*)alloc((size_t)nN * 4);
    int*   gcount  = (int*)  alloc(NBUCK * 4);
    int*   gbase   = (int*)  alloc(NBUCK * 4);
    int*   gcursor = (int*)  alloc(NBUCK * 4);
    int*   rowptr  = (int*)  alloc((size_t)(nN + 1) * 4);
    uint*  binned  = (uint*) alloc((size_t)nE * 4);
    int*   nbr     = (int*)  alloc((size_t)nE * 4);
    bfu*   z0      = (bfu*)  alloc((size_t)nN * 64 * 2);
    bfu*   zB      = (bfu*)  alloc((size_t)nN * 64 * 2);
    bfu*   zC      = (bfu*)  alloc((size_t)nN * 64 * 2);

    // 1. CSR build: hist -> scan -> bin -> per-bucket build (rowptr, dinv, nbr, z0)
    hipMemsetAsync(gcount, 0, NBUCK * 4, stream);
    bucket_hist<<<640, 256, 0, stream>>>(dst, gcount, nE);
    scan_buckets<<<1, NBUCK, 0, stream>>>(gcount, gbase, gcursor);
    bin_edges<<<(nE + 4095) / 4096, 256, 0, stream>>>(src, dst, gcursor, binned, nE);
    build_csr<<<nBk, 512, 0, stream>>>(binned, gbase, gcount, rowptr, dinv, nbr,
                                       (const float4*)x, (ushort4*)z0, nN, nE);

    // 2. zB = bf16(D^-1 (A+I) z0); zC = bf16(D^-1/2 (A+I) zB)
    const int gBlocks = (nN + 3) / 4;
    gather_hop8<2><<<gBlocks, 256, 0, stream>>>(zB, z0, nbr, rowptr, dinv, nN);
    gather_hop8<1><<<gBlocks, 256, 0, stream>>>(zC, zB, nbr, rowptr, dinv, nN);

    // 3. MFMA MLP + log_softmax
    mlp_mfma<<<(nN + 63) / 64, 256, 0, stream>>>(out, zC, W1, b1, W2, b2, nN);
}